// Round 2
// baseline (219.329 us; speedup 1.0000x reference)
//
#include <hip/hip_runtime.h>

#define NPTS 131072

// ---------- folded-weight table layout in d_ws (f32 elements) ----------
constexpr int OFF_SW1 = 0;        // 1024  select_w1 [e*32+c]
constexpr int OFF_BNS = 1024;     // 32    bn scale (gamma/sqrt(var+eps))
constexpr int OFF_BNH = 1056;     // 32    bn shift (beta - mean*scale)
constexpr int OFF_SW2 = 1088;     // 32
constexpr int OFF_B2  = 1120;     // 1
constexpr int OFF_QG  = 1121;     // 608   wq @ Gk^T   [e*19+k]
constexpr int OFF_QGB = 1729;     // 19    bq @ Gk^T
constexpr int OFF_QM  = 1748;     // 96    wq @ Mk^T   [e*3+m]
constexpr int OFF_QMB = 1844;     // 3     bq @ Mk^T
constexpr int OFF_QBV = 1847;     // 32    wq @ bk
constexpr int OFF_QBB = 1879;     // 1     bq . bk
constexpr int OFF_A1  = 1880;     // 608   wt_top @ w_out  [e*19+j]
constexpr int OFF_GVB = 2488;     // 361   Gv @ B  [k*19+j]   (B = wo @ wt_bot @ w_out)
constexpr int OFF_MVB = 2849;     // 57    Mv @ B  [m*19+j]
constexpr int OFF_CV  = 2906;     // 19    bv@B + bo@A2
constexpr int OFF_BB  = 2925;     // 19    bt@w_out + b_out

// =====================================================================
// Kernel 1: fold all weights into d_ws (single block)
// =====================================================================
__global__ __launch_bounds__(256) void precompute_k(
    const float* __restrict__ z,
    const float* __restrict__ sw1,
    const float* __restrict__ bn_gamma,
    const float* __restrict__ bn_beta,
    const float* __restrict__ bn_mean,
    const float* __restrict__ bn_var,
    const float* __restrict__ sw2,
    const float* __restrict__ sb2,
    const float* __restrict__ wq, const float* __restrict__ bq,
    const float* __restrict__ wk, const float* __restrict__ bk,
    const float* __restrict__ wv, const float* __restrict__ bv,
    const float* __restrict__ wo, const float* __restrict__ bo,
    const float* __restrict__ wt, const float* __restrict__ bt,
    const float* __restrict__ wout, const float* __restrict__ bout,
    const float* __restrict__ wgen, const float* __restrict__ bgen,
    float* __restrict__ W)
{
    __shared__ float Lwk[1024], Lwv[1024], Lwq[1024], Lwo[1024];
    __shared__ float Lwt[2048], Lwout[608], Lwgen[1632];
    __shared__ float LG[608], LGk[608], LGv[608], LMk[96], LMv[96];
    __shared__ float LA2[608], LB[608], Lg0[32];

    const int t = threadIdx.x;

    // stage 0: stage raw weights to LDS
    for (int i = t; i < 1024; i += 256) {
        Lwk[i] = wk[i]; Lwv[i] = wv[i];
        Lwq[i] = wq[i]; Lwo[i] = wo[i];
    }
    for (int i = t; i < 2048; i += 256) Lwt[i] = wt[i];
    for (int i = t; i < 608;  i += 256) Lwout[i] = wout[i];
    for (int i = t; i < 1632; i += 256) Lwgen[i] = wgen[i];
    __syncthreads();

    // stage 1: independent folds
    if (t < 32) {
        float g = bgen[t];
        for (int d = 0; d < 16; ++d) g += z[d] * Lwgen[d*32 + t];
        Lg0[t] = g;
        float scale = bn_gamma[t] / sqrtf(bn_var[t] + 1e-4f);
        W[OFF_BNS + t] = scale;
        W[OFF_BNH + t] = bn_beta[t] - bn_mean[t] * scale;
        W[OFF_SW2 + t] = sw2[t];
    }
    if (t == 0) W[OFF_B2] = sb2[0];
    for (int i = t; i < 1024; i += 256) W[OFF_SW1 + i] = sw1[i];
    for (int i = t; i < 96; i += 256) {  // Mk = ws @ wk, Mv = ws @ wv
        int m = i >> 5, c = i & 31;
        float a = 0.f, b = 0.f;
        for (int e = 0; e < 32; ++e) {
            float wsrow = Lwgen[(35 + m)*32 + e];
            a += wsrow * Lwk[e*32 + c];
            b += wsrow * Lwv[e*32 + c];
        }
        LMk[i] = a; LMv[i] = b;
    }
    for (int i = t; i < 608; i += 256) {  // A1 = wt_top @ wout, A2 = wt_bot @ wout
        int e = i / 19, j = i % 19;
        float a1 = 0.f, a2 = 0.f;
        for (int d = 0; d < 32; ++d) {
            float w_ = Lwout[d*19 + j];
            a1 += Lwt[e*32 + d] * w_;
            a2 += Lwt[(32 + e)*32 + d] * w_;
        }
        W[OFF_A1 + i] = a1; LA2[e*19 + j] = a2;
    }
    for (int i = t; i < 19; i += 256) {   // bb = bt@wout + bout
        float a = bout[i];
        for (int d = 0; d < 32; ++d) a += bt[d] * Lwout[d*19 + i];
        W[OFF_BB + i] = a;
    }
    for (int i = t; i < 32; i += 256) {   // qbv = wq @ bk
        float a = 0.f;
        for (int c = 0; c < 32; ++c) a += Lwq[i*32 + c] * bk[c];
        W[OFF_QBV + i] = a;
    }
    if (t == 0) {
        float a = 0.f;
        for (int c = 0; c < 32; ++c) a += bq[c] * bk[c];
        W[OFF_QBB] = a;
    }
    __syncthreads();

    // stage 2: G[k][e] = g0[e] + wc[k][e]
    for (int i = t; i < 608; i += 256) {
        int k = i >> 5, e = i & 31;
        LG[i] = Lg0[e] + Lwgen[(16 + k)*32 + e];
    }
    __syncthreads();

    // stage 3: Gk = G@wk, Gv = G@wv, B = wo@A2, QM, QMB
    for (int i = t; i < 608; i += 256) {
        int k = i >> 5, c = i & 31;
        float a = 0.f, b = 0.f;
        for (int e = 0; e < 32; ++e) {
            float g = LG[k*32 + e];
            a += g * Lwk[e*32 + c];
            b += g * Lwv[e*32 + c];
        }
        LGk[i] = a; LGv[i] = b;
    }
    for (int i = t; i < 608; i += 256) {
        int c = i / 19, j = i % 19;
        float a = 0.f;
        for (int d = 0; d < 32; ++d) a += Lwo[c*32 + d] * LA2[d*19 + j];
        LB[i] = a;
    }
    for (int i = t; i < 96; i += 256) {
        int e = i / 3, m = i % 3;
        float a = 0.f;
        for (int c = 0; c < 32; ++c) a += Lwq[e*32 + c] * LMk[m*32 + c];
        W[OFF_QM + i] = a;
    }
    if (t < 3) {
        float a = 0.f;
        for (int c = 0; c < 32; ++c) a += bq[c] * LMk[t*32 + c];
        W[OFF_QMB + t] = a;
    }
    __syncthreads();

    // stage 4: QG, QGB, GVB, MVB, CV
    for (int i = t; i < 608; i += 256) {
        int e = i / 19, k = i % 19;
        float a = 0.f;
        for (int c = 0; c < 32; ++c) a += Lwq[e*32 + c] * LGk[k*32 + c];
        W[OFF_QG + i] = a;
    }
    for (int i = t; i < 19; i += 256) {
        float a = 0.f;
        for (int c = 0; c < 32; ++c) a += bq[c] * LGk[i*32 + c];
        W[OFF_QGB + i] = a;
    }
    for (int i = t; i < 361; i += 256) {
        int k = i / 19, j = i % 19;
        float a = 0.f;
        for (int c = 0; c < 32; ++c) a += LGv[k*32 + c] * LB[c*19 + j];
        W[OFF_GVB + i] = a;
    }
    for (int i = t; i < 57; i += 256) {
        int m = i / 19, j = i % 19;
        float a = 0.f;
        for (int c = 0; c < 32; ++c) a += LMv[m*32 + c] * LB[c*19 + j];
        W[OFF_MVB + i] = a;
    }
    for (int i = t; i < 19; i += 256) {
        float a = 0.f;
        for (int c = 0; c < 32; ++c) a += bv[c] * LB[c*19 + i];
        for (int d = 0; d < 32; ++d) a += bo[d] * LA2[d*19 + i];
        W[OFF_CV + i] = a;
    }
}

// =====================================================================
// Kernel 2: one point per thread, folded math (all f32)
// =====================================================================
__global__ __launch_bounds__(256) void main_k(
    const float* __restrict__ feat,
    const float* __restrict__ sflow,
    const float* __restrict__ cpred,
    const float* __restrict__ W,
    float* __restrict__ out)
{
    const int n = blockIdx.x * 256 + threadIdx.x;

    // ---- load feat row (32 f32, 128B aligned) ----
    float f[32];
    const float4* fp = (const float4*)(feat + (long)n * 32);
#pragma unroll
    for (int g = 0; g < 8; ++g) {
        float4 v = fp[g];
        f[g*4+0] = v.x; f[g*4+1] = v.y; f[g*4+2] = v.z; f[g*4+3] = v.w;
    }

    // ---- scene_flow + temp mask ----
    float s0 = sflow[(long)n*3 + 0];
    float s1 = sflow[(long)n*3 + 1];
    float s2 = sflow[(long)n*3 + 2];
    bool tmask = (s0 != 0.f) | (s1 != 0.f) | (s2 != 0.f);

    // ---- softmax(coarse_pred) ----
    float cp[19];
#pragma unroll
    for (int k = 0; k < 19; ++k) cp[k] = cpred[(long)n*19 + k];
    float m1 = cp[0];
#pragma unroll
    for (int k = 1; k < 19; ++k) m1 = fmaxf(m1, cp[k]);
    float sum1 = 0.f;
#pragma unroll
    for (int k = 0; k < 19; ++k) { cp[k] = __expf(cp[k] - m1); sum1 += cp[k]; }
    float r1 = 1.f / sum1;
#pragma unroll
    for (int k = 0; k < 19; ++k) cp[k] *= r1;

    // ---- selection score:  s = b2 + sum_c relu(BN(f@W1)[c]) * w2[c] ----
    float sacc = W[OFF_B2];
#pragma unroll
    for (int c = 0; c < 32; ++c) {
        float a = 0.f;
#pragma unroll
        for (int e = 0; e < 32; ++e) a = fmaf(f[e], W[OFF_SW1 + e*32 + c], a);
        float h = fmaf(a, W[OFF_BNS + c], W[OFF_BNH + c]);
        h = fmaxf(h, 0.f);
        sacc = fmaf(h, W[OFF_SW2 + c], sacc);
    }
    // sigmoid(s) < 0.8  <=>  s < ln(4)
    bool valid = tmask && (sacc < 1.3862943611198906f);

    // ---- attention logits via folded weights ----
    float qg[19];
#pragma unroll
    for (int k = 0; k < 19; ++k) qg[k] = W[OFF_QGB + k];
    float qm0 = W[OFF_QMB + 0], qm1 = W[OFF_QMB + 1], qm2 = W[OFF_QMB + 2];
    float qb = W[OFF_QBB];
#pragma unroll
    for (int e = 0; e < 32; ++e) {
        float fe = f[e];
#pragma unroll
        for (int k = 0; k < 19; ++k) qg[k] = fmaf(fe, W[OFF_QG + e*19 + k], qg[k]);
        qm0 = fmaf(fe, W[OFF_QM + e*3 + 0], qm0);
        qm1 = fmaf(fe, W[OFF_QM + e*3 + 1], qm1);
        qm2 = fmaf(fe, W[OFF_QM + e*3 + 2], qm2);
        qb  = fmaf(fe, W[OFF_QBV + e], qb);
    }
    float qs = s0*qm0 + s1*qm1 + s2*qm2;

    const float RS = 0.17677669529663687f;  // 1/sqrt(32)
    float l[19];
#pragma unroll
    for (int k = 0; k < 19; ++k) l[k] = fmaf(cp[k], qg[k] + qs, qb) * RS;

    // ---- softmax(l) → attn;  w[k] = attn[k]*cp[k];  Sw = sum w ----
    float m2 = l[0];
#pragma unroll
    for (int k = 1; k < 19; ++k) m2 = fmaxf(m2, l[k]);
    float sum2 = 0.f;
#pragma unroll
    for (int k = 0; k < 19; ++k) { l[k] = __expf(l[k] - m2); sum2 += l[k]; }
    float r2 = 1.f / sum2;
    float Sw = 0.f;
#pragma unroll
    for (int k = 0; k < 19; ++k) { l[k] = l[k] * r2 * cp[k]; Sw += l[k]; }

    // ---- output: o = bb + f@A1 + valid*(w@GVB + Sw*(sf@MVB) + cv) ----
    float o[19];
#pragma unroll
    for (int j = 0; j < 19; ++j) o[j] = W[OFF_BB + j];
#pragma unroll
    for (int e = 0; e < 32; ++e) {
        float fe = f[e];
#pragma unroll
        for (int j = 0; j < 19; ++j) o[j] = fmaf(fe, W[OFF_A1 + e*19 + j], o[j]);
    }
    float vg = valid ? 1.f : 0.f;
#pragma unroll
    for (int j = 0; j < 19; ++j) {
        float a = W[OFF_CV + j]
                + Sw * (s0 * W[OFF_MVB + j] + s1 * W[OFF_MVB + 19 + j] + s2 * W[OFF_MVB + 38 + j]);
#pragma unroll
        for (int k = 0; k < 19; ++k) a = fmaf(l[k], W[OFF_GVB + k*19 + j], a);
        o[j] = fmaf(vg, a, o[j]);
    }

    // ---- store 19 f32 ----
    float* op = out + (long)n * 19;
#pragma unroll
    for (int j = 0; j < 19; ++j) op[j] = o[j];
}

// =====================================================================
extern "C" void kernel_launch(void* const* d_in, const int* in_sizes, int n_in,
                              void* d_out, int out_size, void* d_ws, size_t ws_size,
                              hipStream_t stream) {
    const float* feat  = (const float*)d_in[0];
    const float* sflow = (const float*)d_in[1];
    const float* cpred = (const float*)d_in[2];
    const float* z     = (const float*)d_in[3];
    const float* sw1   = (const float*)d_in[4];
    const float* bn_g  = (const float*)d_in[5];
    const float* bn_b  = (const float*)d_in[6];
    const float* bn_m  = (const float*)d_in[7];
    const float* bn_v  = (const float*)d_in[8];
    const float* sw2   = (const float*)d_in[9];
    const float* sb2   = (const float*)d_in[10];
    const float* wq    = (const float*)d_in[11];
    const float* bq    = (const float*)d_in[12];
    const float* wk    = (const float*)d_in[13];
    const float* bk    = (const float*)d_in[14];
    const float* wv    = (const float*)d_in[15];
    const float* bv    = (const float*)d_in[16];
    const float* wo    = (const float*)d_in[17];
    const float* bo    = (const float*)d_in[18];
    const float* wt    = (const float*)d_in[19];
    const float* bt    = (const float*)d_in[20];
    const float* wout  = (const float*)d_in[21];
    const float* bout  = (const float*)d_in[22];
    const float* wgen  = (const float*)d_in[23];
    const float* bgen  = (const float*)d_in[24];

    float* W = (float*)d_ws;

    hipLaunchKernelGGL(precompute_k, dim3(1), dim3(256), 0, stream,
                       z, sw1, bn_g, bn_b, bn_m, bn_v, sw2, sb2,
                       wq, bq, wk, bk, wv, bv, wo, bo, wt, bt,
                       wout, bout, wgen, bgen, W);

    hipLaunchKernelGGL(main_k, dim3(NPTS / 256), dim3(256), 0, stream,
                       feat, sflow, cpred, W, (float*)d_out);
}

// Round 3
// 218.891 us; speedup vs baseline: 1.0020x; 1.0020x over previous
//
#include <hip/hip_runtime.h>

#define NPTS 131072

// ---------- folded-weight table layout in d_ws (f32 elements) ----------
constexpr int OFF_SW1 = 0;        // 1024  select_w1 [e*32+c]
constexpr int OFF_BNS = 1024;     // 32    bn scale (gamma/sqrt(var+eps))
constexpr int OFF_BNH = 1056;     // 32    bn shift (beta - mean*scale)
constexpr int OFF_SW2 = 1088;     // 32
constexpr int OFF_B2  = 1120;     // 1
constexpr int OFF_QG  = 1121;     // 608   wq @ Gk^T   [e*19+k]
constexpr int OFF_QGB = 1729;     // 19    bq @ Gk^T
constexpr int OFF_QM  = 1748;     // 96    wq @ Mk^T   [e*3+m]
constexpr int OFF_QMB = 1844;     // 3     bq @ Mk^T
constexpr int OFF_QBV = 1847;     // 32    wq @ bk
constexpr int OFF_QBB = 1879;     // 1     bq . bk
constexpr int OFF_A1  = 1880;     // 608   wt_top @ w_out  [e*19+j]
constexpr int OFF_GVB = 2488;     // 361   Gv @ B  [k*19+j]   (B = wo @ wt_bot @ w_out)
constexpr int OFF_MVB = 2849;     // 57    Mv @ B  [m*19+j]
constexpr int OFF_CV  = 2906;     // 19    bv@B + bo@A2
constexpr int OFF_BB  = 2925;     // 19    bt@w_out + b_out

// =====================================================================
// Kernel 1: fold all weights into d_ws (single block)
// =====================================================================
__global__ __launch_bounds__(256) void precompute_k(
    const float* __restrict__ z,
    const float* __restrict__ sw1,
    const float* __restrict__ bn_gamma,
    const float* __restrict__ bn_beta,
    const float* __restrict__ bn_mean,
    const float* __restrict__ bn_var,
    const float* __restrict__ sw2,
    const float* __restrict__ sb2,
    const float* __restrict__ wq, const float* __restrict__ bq,
    const float* __restrict__ wk, const float* __restrict__ bk,
    const float* __restrict__ wv, const float* __restrict__ bv,
    const float* __restrict__ wo, const float* __restrict__ bo,
    const float* __restrict__ wt, const float* __restrict__ bt,
    const float* __restrict__ wout, const float* __restrict__ bout,
    const float* __restrict__ wgen, const float* __restrict__ bgen,
    float* __restrict__ W)
{
    __shared__ float Lwk[1024], Lwv[1024], Lwq[1024], Lwo[1024];
    __shared__ float Lwt[2048], Lwout[608], Lwgen[1632];
    __shared__ float LG[608], LGk[608], LGv[608], LMk[96], LMv[96];
    __shared__ float LA2[608], LB[608], Lg0[32];

    const int t = threadIdx.x;

    // stage 0: stage raw weights to LDS
    for (int i = t; i < 1024; i += 256) {
        Lwk[i] = wk[i]; Lwv[i] = wv[i];
        Lwq[i] = wq[i]; Lwo[i] = wo[i];
    }
    for (int i = t; i < 2048; i += 256) Lwt[i] = wt[i];
    for (int i = t; i < 608;  i += 256) Lwout[i] = wout[i];
    for (int i = t; i < 1632; i += 256) Lwgen[i] = wgen[i];
    __syncthreads();

    // stage 1: independent folds
    if (t < 32) {
        float g = bgen[t];
        for (int d = 0; d < 16; ++d) g += z[d] * Lwgen[d*32 + t];
        Lg0[t] = g;
        float scale = bn_gamma[t] / sqrtf(bn_var[t] + 1e-4f);
        W[OFF_BNS + t] = scale;
        W[OFF_BNH + t] = bn_beta[t] - bn_mean[t] * scale;
        W[OFF_SW2 + t] = sw2[t];
    }
    if (t == 0) W[OFF_B2] = sb2[0];
    for (int i = t; i < 1024; i += 256) W[OFF_SW1 + i] = sw1[i];
    for (int i = t; i < 96; i += 256) {  // Mk = ws @ wk, Mv = ws @ wv
        int m = i >> 5, c = i & 31;
        float a = 0.f, b = 0.f;
        for (int e = 0; e < 32; ++e) {
            float wsrow = Lwgen[(35 + m)*32 + e];
            a += wsrow * Lwk[e*32 + c];
            b += wsrow * Lwv[e*32 + c];
        }
        LMk[i] = a; LMv[i] = b;
    }
    for (int i = t; i < 608; i += 256) {  // A1 = wt_top @ wout, A2 = wt_bot @ wout
        int e = i / 19, j = i % 19;
        float a1 = 0.f, a2 = 0.f;
        for (int d = 0; d < 32; ++d) {
            float w_ = Lwout[d*19 + j];
            a1 += Lwt[e*32 + d] * w_;
            a2 += Lwt[(32 + e)*32 + d] * w_;
        }
        W[OFF_A1 + i] = a1; LA2[e*19 + j] = a2;
    }
    for (int i = t; i < 19; i += 256) {   // bb = bt@wout + bout
        float a = bout[i];
        for (int d = 0; d < 32; ++d) a += bt[d] * Lwout[d*19 + i];
        W[OFF_BB + i] = a;
    }
    for (int i = t; i < 32; i += 256) {   // qbv = wq @ bk
        float a = 0.f;
        for (int c = 0; c < 32; ++c) a += Lwq[i*32 + c] * bk[c];
        W[OFF_QBV + i] = a;
    }
    if (t == 0) {
        float a = 0.f;
        for (int c = 0; c < 32; ++c) a += bq[c] * bk[c];
        W[OFF_QBB] = a;
    }
    __syncthreads();

    // stage 2: G[k][e] = g0[e] + wc[k][e]
    for (int i = t; i < 608; i += 256) {
        int k = i >> 5, e = i & 31;
        LG[i] = Lg0[e] + Lwgen[(16 + k)*32 + e];
    }
    __syncthreads();

    // stage 3: Gk = G@wk, Gv = G@wv, B = wo@A2, QM, QMB
    for (int i = t; i < 608; i += 256) {
        int k = i >> 5, c = i & 31;
        float a = 0.f, b = 0.f;
        for (int e = 0; e < 32; ++e) {
            float g = LG[k*32 + e];
            a += g * Lwk[e*32 + c];
            b += g * Lwv[e*32 + c];
        }
        LGk[i] = a; LGv[i] = b;
    }
    for (int i = t; i < 608; i += 256) {
        int c = i / 19, j = i % 19;
        float a = 0.f;
        for (int d = 0; d < 32; ++d) a += Lwo[c*32 + d] * LA2[d*19 + j];
        LB[i] = a;
    }
    for (int i = t; i < 96; i += 256) {
        int e = i / 3, m = i % 3;
        float a = 0.f;
        for (int c = 0; c < 32; ++c) a += Lwq[e*32 + c] * LMk[m*32 + c];
        W[OFF_QM + i] = a;
    }
    if (t < 3) {
        float a = 0.f;
        for (int c = 0; c < 32; ++c) a += bq[c] * LMk[t*32 + c];
        W[OFF_QMB + t] = a;
    }
    __syncthreads();

    // stage 4: QG, QGB, GVB, MVB, CV
    for (int i = t; i < 608; i += 256) {
        int e = i / 19, k = i % 19;
        float a = 0.f;
        for (int c = 0; c < 32; ++c) a += Lwq[e*32 + c] * LGk[k*32 + c];
        W[OFF_QG + i] = a;
    }
    for (int i = t; i < 19; i += 256) {
        float a = 0.f;
        for (int c = 0; c < 32; ++c) a += bq[c] * LGk[i*32 + c];
        W[OFF_QGB + i] = a;
    }
    for (int i = t; i < 361; i += 256) {
        int k = i / 19, j = i % 19;
        float a = 0.f;
        for (int c = 0; c < 32; ++c) a += LGv[k*32 + c] * LB[c*19 + j];
        W[OFF_GVB + i] = a;
    }
    for (int i = t; i < 57; i += 256) {
        int m = i / 19, j = i % 19;
        float a = 0.f;
        for (int c = 0; c < 32; ++c) a += LMv[m*32 + c] * LB[c*19 + j];
        W[OFF_MVB + i] = a;
    }
    for (int i = t; i < 19; i += 256) {
        float a = 0.f;
        for (int c = 0; c < 32; ++c) a += bv[c] * LB[c*19 + i];
        for (int d = 0; d < 32; ++d) a += bo[d] * LA2[d*19 + i];
        W[OFF_CV + i] = a;
    }
}

// =====================================================================
// Kernel 2: one point per thread, folded math (all f32)
// __launch_bounds__(256, 1): grid is only 2 blocks/CU (8 waves/CU), so a
// 256-VGPR budget costs no achievable occupancy. Without the min-waves
// arg the allocator capped at 60 VGPRs and spilled f[32]/cp/l/qg/o to
// scratch -> 98 us. Keep everything register-resident.
// =====================================================================
__global__ __launch_bounds__(256, 1) void main_k(
    const float* __restrict__ feat,
    const float* __restrict__ sflow,
    const float* __restrict__ cpred,
    const float* __restrict__ W,
    float* __restrict__ out)
{
    const int n = blockIdx.x * 256 + threadIdx.x;

    // ---- load feat row (32 f32, 128B aligned) ----
    float f[32];
    const float4* fp = (const float4*)(feat + (long)n * 32);
#pragma unroll
    for (int g = 0; g < 8; ++g) {
        float4 v = fp[g];
        f[g*4+0] = v.x; f[g*4+1] = v.y; f[g*4+2] = v.z; f[g*4+3] = v.w;
    }

    // ---- scene_flow + temp mask ----
    float s0 = sflow[(long)n*3 + 0];
    float s1 = sflow[(long)n*3 + 1];
    float s2 = sflow[(long)n*3 + 2];
    bool tmask = (s0 != 0.f) | (s1 != 0.f) | (s2 != 0.f);

    // ---- softmax(coarse_pred) ----
    float cp[19];
#pragma unroll
    for (int k = 0; k < 19; ++k) cp[k] = cpred[(long)n*19 + k];
    float m1 = cp[0];
#pragma unroll
    for (int k = 1; k < 19; ++k) m1 = fmaxf(m1, cp[k]);
    float sum1 = 0.f;
#pragma unroll
    for (int k = 0; k < 19; ++k) { cp[k] = __expf(cp[k] - m1); sum1 += cp[k]; }
    float r1 = 1.f / sum1;
#pragma unroll
    for (int k = 0; k < 19; ++k) cp[k] *= r1;

    // ---- selection score:  s = b2 + sum_c relu(BN(f@W1)[c]) * w2[c] ----
    float sacc = W[OFF_B2];
#pragma unroll
    for (int c = 0; c < 32; ++c) {
        float a = 0.f;
#pragma unroll
        for (int e = 0; e < 32; ++e) a = fmaf(f[e], W[OFF_SW1 + e*32 + c], a);
        float h = fmaf(a, W[OFF_BNS + c], W[OFF_BNH + c]);
        h = fmaxf(h, 0.f);
        sacc = fmaf(h, W[OFF_SW2 + c], sacc);
    }
    // sigmoid(s) < 0.8  <=>  s < ln(4)
    bool valid = tmask && (sacc < 1.3862943611198906f);

    // ---- attention logits via folded weights ----
    float qg[19];
#pragma unroll
    for (int k = 0; k < 19; ++k) qg[k] = W[OFF_QGB + k];
    float qm0 = W[OFF_QMB + 0], qm1 = W[OFF_QMB + 1], qm2 = W[OFF_QMB + 2];
    float qb = W[OFF_QBB];
#pragma unroll
    for (int e = 0; e < 32; ++e) {
        float fe = f[e];
#pragma unroll
        for (int k = 0; k < 19; ++k) qg[k] = fmaf(fe, W[OFF_QG + e*19 + k], qg[k]);
        qm0 = fmaf(fe, W[OFF_QM + e*3 + 0], qm0);
        qm1 = fmaf(fe, W[OFF_QM + e*3 + 1], qm1);
        qm2 = fmaf(fe, W[OFF_QM + e*3 + 2], qm2);
        qb  = fmaf(fe, W[OFF_QBV + e], qb);
    }
    float qs = s0*qm0 + s1*qm1 + s2*qm2;

    const float RS = 0.17677669529663687f;  // 1/sqrt(32)
    float l[19];
#pragma unroll
    for (int k = 0; k < 19; ++k) l[k] = fmaf(cp[k], qg[k] + qs, qb) * RS;

    // ---- softmax(l) → attn;  w[k] = attn[k]*cp[k];  Sw = sum w ----
    float m2 = l[0];
#pragma unroll
    for (int k = 1; k < 19; ++k) m2 = fmaxf(m2, l[k]);
    float sum2 = 0.f;
#pragma unroll
    for (int k = 0; k < 19; ++k) { l[k] = __expf(l[k] - m2); sum2 += l[k]; }
    float r2 = 1.f / sum2;
    float Sw = 0.f;
#pragma unroll
    for (int k = 0; k < 19; ++k) { l[k] = l[k] * r2 * cp[k]; Sw += l[k]; }

    // ---- output: o = bb + f@A1 + valid*(w@GVB + Sw*(sf@MVB) + cv) ----
    float o[19];
#pragma unroll
    for (int j = 0; j < 19; ++j) o[j] = W[OFF_BB + j];
#pragma unroll
    for (int e = 0; e < 32; ++e) {
        float fe = f[e];
#pragma unroll
        for (int j = 0; j < 19; ++j) o[j] = fmaf(fe, W[OFF_A1 + e*19 + j], o[j]);
    }
    float vg = valid ? 1.f : 0.f;
#pragma unroll
    for (int j = 0; j < 19; ++j) {
        float a = W[OFF_CV + j]
                + Sw * (s0 * W[OFF_MVB + j] + s1 * W[OFF_MVB + 19 + j] + s2 * W[OFF_MVB + 38 + j]);
#pragma unroll
        for (int k = 0; k < 19; ++k) a = fmaf(l[k], W[OFF_GVB + k*19 + j], a);
        o[j] = fmaf(vg, a, o[j]);
    }

    // ---- store 19 f32 ----
    float* op = out + (long)n * 19;
#pragma unroll
    for (int j = 0; j < 19; ++j) op[j] = o[j];
}

// =====================================================================
extern "C" void kernel_launch(void* const* d_in, const int* in_sizes, int n_in,
                              void* d_out, int out_size, void* d_ws, size_t ws_size,
                              hipStream_t stream) {
    const float* feat  = (const float*)d_in[0];
    const float* sflow = (const float*)d_in[1];
    const float* cpred = (const float*)d_in[2];
    const float* z     = (const float*)d_in[3];
    const float* sw1   = (const float*)d_in[4];
    const float* bn_g  = (const float*)d_in[5];
    const float* bn_b  = (const float*)d_in[6];
    const float* bn_m  = (const float*)d_in[7];
    const float* bn_v  = (const float*)d_in[8];
    const float* sw2   = (const float*)d_in[9];
    const float* sb2   = (const float*)d_in[10];
    const float* wq    = (const float*)d_in[11];
    const float* bq    = (const float*)d_in[12];
    const float* wk    = (const float*)d_in[13];
    const float* bk    = (const float*)d_in[14];
    const float* wv    = (const float*)d_in[15];
    const float* bv    = (const float*)d_in[16];
    const float* wo    = (const float*)d_in[17];
    const float* bo    = (const float*)d_in[18];
    const float* wt    = (const float*)d_in[19];
    const float* bt    = (const float*)d_in[20];
    const float* wout  = (const float*)d_in[21];
    const float* bout  = (const float*)d_in[22];
    const float* wgen  = (const float*)d_in[23];
    const float* bgen  = (const float*)d_in[24];

    float* W = (float*)d_ws;

    hipLaunchKernelGGL(precompute_k, dim3(1), dim3(256), 0, stream,
                       z, sw1, bn_g, bn_b, bn_m, bn_v, sw2, sb2,
                       wq, bq, wk, bk, wv, bv, wo, bo, wt, bt,
                       wout, bout, wgen, bgen, W);

    hipLaunchKernelGGL(main_k, dim3(NPTS / 256), dim3(256), 0, stream,
                       feat, sflow, cpred, W, (float*)d_out);
}

// Round 4
// 171.724 us; speedup vs baseline: 1.2772x; 1.2747x over previous
//
#include <hip/hip_runtime.h>

#define NPTS 131072

// ---------- folded-weight table layout in d_ws (f32 elements) ----------
constexpr int OFF_SW1 = 0;        // 1024  select_w1 TRANSPOSED [c*32+e]
constexpr int OFF_BNS = 1024;     // 32    bn scale (gamma/sqrt(var+eps))
constexpr int OFF_BNH = 1056;     // 32    bn shift (beta - mean*scale)
constexpr int OFF_SW2 = 1088;     // 32
constexpr int OFF_B2  = 1120;     // 1
constexpr int OFF_QG  = 1121;     // 608   wq @ Gk^T   [e*19+k]
constexpr int OFF_QGB = 1729;     // 19    bq @ Gk^T
constexpr int OFF_QM  = 1748;     // 96    wq @ Mk^T   [e*3+m]
constexpr int OFF_QMB = 1844;     // 3     bq @ Mk^T
constexpr int OFF_QBV = 1847;     // 32    wq @ bk
constexpr int OFF_QBB = 1879;     // 1     bq . bk
constexpr int OFF_A1  = 1880;     // 608   wt_top @ w_out  [e*19+j]
constexpr int OFF_GVB = 2488;     // 361   Gv @ B  [k*19+j]   (B = wo @ wt_bot @ w_out)
constexpr int OFF_MVB = 2849;     // 57    Mv @ B  [m*19+j]
constexpr int OFF_CV  = 2906;     // 19    bv@B + bo@A2
constexpr int OFF_BB  = 2925;     // 19    bt@w_out + b_out

// Constant-address-space cast (composable_kernel idiom): lane-uniform loads
// through this pointer compile to s_load -> SGPR, so FMAs read the weight as
// a scalar operand instead of doing per-lane VMEM + addressing VALU.
#define CONST_AS __attribute__((address_space(4)))
__device__ __forceinline__ const CONST_AS float* to_const(const float* p) {
    return (const CONST_AS float*)p;
}

// =====================================================================
// Kernel 1: fold all weights into d_ws (single block)
// =====================================================================
__global__ __launch_bounds__(256) void precompute_k(
    const float* __restrict__ z,
    const float* __restrict__ sw1,
    const float* __restrict__ bn_gamma,
    const float* __restrict__ bn_beta,
    const float* __restrict__ bn_mean,
    const float* __restrict__ bn_var,
    const float* __restrict__ sw2,
    const float* __restrict__ sb2,
    const float* __restrict__ wq, const float* __restrict__ bq,
    const float* __restrict__ wk, const float* __restrict__ bk,
    const float* __restrict__ wv, const float* __restrict__ bv,
    const float* __restrict__ wo, const float* __restrict__ bo,
    const float* __restrict__ wt, const float* __restrict__ bt,
    const float* __restrict__ wout, const float* __restrict__ bout,
    const float* __restrict__ wgen, const float* __restrict__ bgen,
    float* __restrict__ W)
{
    __shared__ float Lwk[1024], Lwv[1024], Lwq[1024], Lwo[1024];
    __shared__ float Lwt[2048], Lwout[608], Lwgen[1632];
    __shared__ float LG[608], LGk[608], LGv[608], LMk[96], LMv[96];
    __shared__ float LA2[608], LB[608], Lg0[32];

    const int t = threadIdx.x;

    // stage 0: stage raw weights to LDS
    for (int i = t; i < 1024; i += 256) {
        Lwk[i] = wk[i]; Lwv[i] = wv[i];
        Lwq[i] = wq[i]; Lwo[i] = wo[i];
    }
    for (int i = t; i < 2048; i += 256) Lwt[i] = wt[i];
    for (int i = t; i < 608;  i += 256) Lwout[i] = wout[i];
    for (int i = t; i < 1632; i += 256) Lwgen[i] = wgen[i];
    __syncthreads();

    // stage 1: independent folds
    if (t < 32) {
        float g = bgen[t];
        for (int d = 0; d < 16; ++d) g += z[d] * Lwgen[d*32 + t];
        Lg0[t] = g;
        float scale = bn_gamma[t] / sqrtf(bn_var[t] + 1e-4f);
        W[OFF_BNS + t] = scale;
        W[OFF_BNH + t] = bn_beta[t] - bn_mean[t] * scale;
        W[OFF_SW2 + t] = sw2[t];
    }
    if (t == 0) W[OFF_B2] = sb2[0];
    // SW1 transposed: SW1T[c*32+e] = sw1[e*32+c]  (row-contiguous per c)
    for (int i = t; i < 1024; i += 256) W[OFF_SW1 + i] = sw1[(i & 31)*32 + (i >> 5)];
    for (int i = t; i < 96; i += 256) {  // Mk = ws @ wk, Mv = ws @ wv
        int m = i >> 5, c = i & 31;
        float a = 0.f, b = 0.f;
        for (int e = 0; e < 32; ++e) {
            float wsrow = Lwgen[(35 + m)*32 + e];
            a += wsrow * Lwk[e*32 + c];
            b += wsrow * Lwv[e*32 + c];
        }
        LMk[i] = a; LMv[i] = b;
    }
    for (int i = t; i < 608; i += 256) {  // A1 = wt_top @ wout, A2 = wt_bot @ wout
        int e = i / 19, j = i % 19;
        float a1 = 0.f, a2 = 0.f;
        for (int d = 0; d < 32; ++d) {
            float w_ = Lwout[d*19 + j];
            a1 += Lwt[e*32 + d] * w_;
            a2 += Lwt[(32 + e)*32 + d] * w_;
        }
        W[OFF_A1 + i] = a1; LA2[e*19 + j] = a2;
    }
    for (int i = t; i < 19; i += 256) {   // bb = bt@wout + bout
        float a = bout[i];
        for (int d = 0; d < 32; ++d) a += bt[d] * Lwout[d*19 + i];
        W[OFF_BB + i] = a;
    }
    for (int i = t; i < 32; i += 256) {   // qbv = wq @ bk
        float a = 0.f;
        for (int c = 0; c < 32; ++c) a += Lwq[i*32 + c] * bk[c];
        W[OFF_QBV + i] = a;
    }
    if (t == 0) {
        float a = 0.f;
        for (int c = 0; c < 32; ++c) a += bq[c] * bk[c];
        W[OFF_QBB] = a;
    }
    __syncthreads();

    // stage 2: G[k][e] = g0[e] + wc[k][e]
    for (int i = t; i < 608; i += 256) {
        int k = i >> 5, e = i & 31;
        LG[i] = Lg0[e] + Lwgen[(16 + k)*32 + e];
    }
    __syncthreads();

    // stage 3: Gk = G@wk, Gv = G@wv, B = wo@A2, QM, QMB
    for (int i = t; i < 608; i += 256) {
        int k = i >> 5, c = i & 31;
        float a = 0.f, b = 0.f;
        for (int e = 0; e < 32; ++e) {
            float g = LG[k*32 + e];
            a += g * Lwk[e*32 + c];
            b += g * Lwv[e*32 + c];
        }
        LGk[i] = a; LGv[i] = b;
    }
    for (int i = t; i < 608; i += 256) {
        int c = i / 19, j = i % 19;
        float a = 0.f;
        for (int d = 0; d < 32; ++d) a += Lwo[c*32 + d] * LA2[d*19 + j];
        LB[i] = a;
    }
    for (int i = t; i < 96; i += 256) {
        int e = i / 3, m = i % 3;
        float a = 0.f;
        for (int c = 0; c < 32; ++c) a += Lwq[e*32 + c] * LMk[m*32 + c];
        W[OFF_QM + i] = a;
    }
    if (t < 3) {
        float a = 0.f;
        for (int c = 0; c < 32; ++c) a += bq[c] * LMk[t*32 + c];
        W[OFF_QMB + t] = a;
    }
    __syncthreads();

    // stage 4: QG, QGB, GVB, MVB, CV
    for (int i = t; i < 608; i += 256) {
        int e = i / 19, k = i % 19;
        float a = 0.f;
        for (int c = 0; c < 32; ++c) a += Lwq[e*32 + c] * LGk[k*32 + c];
        W[OFF_QG + i] = a;
    }
    for (int i = t; i < 19; i += 256) {
        float a = 0.f;
        for (int c = 0; c < 32; ++c) a += bq[c] * LGk[i*32 + c];
        W[OFF_QGB + i] = a;
    }
    for (int i = t; i < 361; i += 256) {
        int k = i / 19, j = i % 19;
        float a = 0.f;
        for (int c = 0; c < 32; ++c) a += LGv[k*32 + c] * LB[c*19 + j];
        W[OFF_GVB + i] = a;
    }
    for (int i = t; i < 57; i += 256) {
        int m = i / 19, j = i % 19;
        float a = 0.f;
        for (int c = 0; c < 32; ++c) a += LMv[m*32 + c] * LB[c*19 + j];
        W[OFF_MVB + i] = a;
    }
    for (int i = t; i < 19; i += 256) {
        float a = 0.f;
        for (int c = 0; c < 32; ++c) a += bv[c] * LB[c*19 + i];
        for (int d = 0; d < 32; ++d) a += bo[d] * LA2[d*19 + i];
        W[OFF_CV + i] = a;
    }
}

// =====================================================================
// Kernel 2: one point per thread; weights via constant addrspace (s_load)
// =====================================================================
__global__ __launch_bounds__(256, 1) void main_k(
    const float* __restrict__ feat,
    const float* __restrict__ sflow,
    const float* __restrict__ cpred,
    const float* __restrict__ Wg,
    float* __restrict__ out)
{
    const CONST_AS float* W = to_const(Wg);
    const int n = blockIdx.x * 256 + threadIdx.x;

    // ---- load feat row (32 f32, 128B aligned) ----
    float f[32];
    const float4* fp = (const float4*)(feat + (long)n * 32);
#pragma unroll
    for (int g = 0; g < 8; ++g) {
        float4 v = fp[g];
        f[g*4+0] = v.x; f[g*4+1] = v.y; f[g*4+2] = v.z; f[g*4+3] = v.w;
    }

    // ---- scene_flow + temp mask ----
    float s0 = sflow[(long)n*3 + 0];
    float s1 = sflow[(long)n*3 + 1];
    float s2 = sflow[(long)n*3 + 2];
    bool tmask = (s0 != 0.f) | (s1 != 0.f) | (s2 != 0.f);

    // ---- softmax(coarse_pred) ----
    float cp[19];
#pragma unroll
    for (int k = 0; k < 19; ++k) cp[k] = cpred[(long)n*19 + k];
    float m1 = cp[0];
#pragma unroll
    for (int k = 1; k < 19; ++k) m1 = fmaxf(m1, cp[k]);
    float sum1 = 0.f;
#pragma unroll
    for (int k = 0; k < 19; ++k) { cp[k] = __expf(cp[k] - m1); sum1 += cp[k]; }
    float r1 = 1.f / sum1;
#pragma unroll
    for (int k = 0; k < 19; ++k) cp[k] *= r1;

    // ---- selection score: SW1T row-contiguous per c ----
    float sacc = W[OFF_B2];
#pragma unroll
    for (int c = 0; c < 32; ++c) {
        float a = 0.f;
#pragma unroll
        for (int e = 0; e < 32; ++e) a = fmaf(f[e], W[OFF_SW1 + c*32 + e], a);
        float h = fmaf(a, W[OFF_BNS + c], W[OFF_BNH + c]);
        h = fmaxf(h, 0.f);
        sacc = fmaf(h, W[OFF_SW2 + c], sacc);
    }
    // sigmoid(s) < 0.8  <=>  s < ln(4)
    bool valid = tmask && (sacc < 1.3862943611198906f);

    // ---- attention logits via folded weights ----
    float qg[19];
#pragma unroll
    for (int k = 0; k < 19; ++k) qg[k] = W[OFF_QGB + k];
    float qm0 = W[OFF_QMB + 0], qm1 = W[OFF_QMB + 1], qm2 = W[OFF_QMB + 2];
    float qb = W[OFF_QBB];
#pragma unroll
    for (int e = 0; e < 32; ++e) {
        float fe = f[e];
#pragma unroll
        for (int k = 0; k < 19; ++k) qg[k] = fmaf(fe, W[OFF_QG + e*19 + k], qg[k]);
        qm0 = fmaf(fe, W[OFF_QM + e*3 + 0], qm0);
        qm1 = fmaf(fe, W[OFF_QM + e*3 + 1], qm1);
        qm2 = fmaf(fe, W[OFF_QM + e*3 + 2], qm2);
        qb  = fmaf(fe, W[OFF_QBV + e], qb);
    }
    float qs = s0*qm0 + s1*qm1 + s2*qm2;

    const float RS = 0.17677669529663687f;  // 1/sqrt(32)
    float l[19];
#pragma unroll
    for (int k = 0; k < 19; ++k) l[k] = fmaf(cp[k], qg[k] + qs, qb) * RS;

    // ---- softmax(l) → attn;  w[k] = attn[k]*cp[k];  Sw = sum w ----
    float m2 = l[0];
#pragma unroll
    for (int k = 1; k < 19; ++k) m2 = fmaxf(m2, l[k]);
    float sum2 = 0.f;
#pragma unroll
    for (int k = 0; k < 19; ++k) { l[k] = __expf(l[k] - m2); sum2 += l[k]; }
    float r2 = 1.f / sum2;
    float Sw = 0.f;
#pragma unroll
    for (int k = 0; k < 19; ++k) { l[k] = l[k] * r2 * cp[k]; Sw += l[k]; }

    // ---- o = bb + f@A1 ----
    float o[19];
#pragma unroll
    for (int j = 0; j < 19; ++j) o[j] = W[OFF_BB + j];
#pragma unroll
    for (int e = 0; e < 32; ++e) {
        float fe = f[e];
#pragma unroll
        for (int j = 0; j < 19; ++j) o[j] = fmaf(fe, W[OFF_A1 + e*19 + j], o[j]);
    }

    // ---- gated part: a2 = cv + Sw*(sf@MVB) + w@GVB  (row-contiguous loops) ----
    float a2[19];
#pragma unroll
    for (int j = 0; j < 19; ++j) a2[j] = W[OFF_CV + j];
    float c0 = Sw * s0, c1 = Sw * s1, c2 = Sw * s2;
#pragma unroll
    for (int j = 0; j < 19; ++j) a2[j] = fmaf(c0, W[OFF_MVB + j], a2[j]);
#pragma unroll
    for (int j = 0; j < 19; ++j) a2[j] = fmaf(c1, W[OFF_MVB + 19 + j], a2[j]);
#pragma unroll
    for (int j = 0; j < 19; ++j) a2[j] = fmaf(c2, W[OFF_MVB + 38 + j], a2[j]);
#pragma unroll
    for (int k = 0; k < 19; ++k) {
        float lk = l[k];
#pragma unroll
        for (int j = 0; j < 19; ++j) a2[j] = fmaf(lk, W[OFF_GVB + k*19 + j], a2[j]);
    }

    float vg = valid ? 1.f : 0.f;
    // ---- store 19 f32 ----
    float* op = out + (long)n * 19;
#pragma unroll
    for (int j = 0; j < 19; ++j) op[j] = fmaf(vg, a2[j], o[j]);
}

// =====================================================================
extern "C" void kernel_launch(void* const* d_in, const int* in_sizes, int n_in,
                              void* d_out, int out_size, void* d_ws, size_t ws_size,
                              hipStream_t stream) {
    const float* feat  = (const float*)d_in[0];
    const float* sflow = (const float*)d_in[1];
    const float* cpred = (const float*)d_in[2];
    const float* z     = (const float*)d_in[3];
    const float* sw1   = (const float*)d_in[4];
    const float* bn_g  = (const float*)d_in[5];
    const float* bn_b  = (const float*)d_in[6];
    const float* bn_m  = (const float*)d_in[7];
    const float* bn_v  = (const float*)d_in[8];
    const float* sw2   = (const float*)d_in[9];
    const float* sb2   = (const float*)d_in[10];
    const float* wq    = (const float*)d_in[11];
    const float* bq    = (const float*)d_in[12];
    const float* wk    = (const float*)d_in[13];
    const float* bk    = (const float*)d_in[14];
    const float* wv    = (const float*)d_in[15];
    const float* bv    = (const float*)d_in[16];
    const float* wo    = (const float*)d_in[17];
    const float* bo    = (const float*)d_in[18];
    const float* wt    = (const float*)d_in[19];
    const float* bt    = (const float*)d_in[20];
    const float* wout  = (const float*)d_in[21];
    const float* bout  = (const float*)d_in[22];
    const float* wgen  = (const float*)d_in[23];
    const float* bgen  = (const float*)d_in[24];

    float* W = (float*)d_ws;

    hipLaunchKernelGGL(precompute_k, dim3(1), dim3(256), 0, stream,
                       z, sw1, bn_g, bn_b, bn_m, bn_v, sw2, sb2,
                       wq, bq, wk, bk, wv, bv, wo, bo, wt, bt,
                       wout, bout, wgen, bgen, W);

    hipLaunchKernelGGL(main_k, dim3(NPTS / 256), dim3(256), 0, stream,
                       feat, sflow, cpred, W, (float*)d_out);
}

// Round 5
// 165.702 us; speedup vs baseline: 1.3236x; 1.0363x over previous
//
#include <hip/hip_runtime.h>

#define NPTS 131072

// ---------- folded-weight table layout in d_ws (f32 elements) ----------
constexpr int OFF_SW1 = 0;        // 1024  select_w1 TRANSPOSED [c*32+e]
constexpr int OFF_BNS = 1024;     // 32    bn scale (gamma/sqrt(var+eps))
constexpr int OFF_BNH = 1056;     // 32    bn shift (beta - mean*scale)
constexpr int OFF_SW2 = 1088;     // 32
constexpr int OFF_B2  = 1120;     // 1
constexpr int OFF_QG  = 1121;     // 608   wq @ Gk^T   [e*19+k]
constexpr int OFF_QGB = 1729;     // 19    bq @ Gk^T
constexpr int OFF_QM  = 1748;     // 96    wq @ Mk^T   [e*3+m]
constexpr int OFF_QMB = 1844;     // 3     bq @ Mk^T
constexpr int OFF_QBV = 1847;     // 32    wq @ bk
constexpr int OFF_QBB = 1879;     // 1     bq . bk
constexpr int OFF_A1  = 1880;     // 608   wt_top @ w_out  [e*19+j]
constexpr int OFF_GVB = 2488;     // 361   Gv @ B  [k*19+j]   (B = wo @ wt_bot @ w_out)
constexpr int OFF_MVB = 2849;     // 57    Mv @ B  [m*19+j]
constexpr int OFF_CV  = 2906;     // 19    bv@B + bo@A2
constexpr int OFF_BB  = 2925;     // 19    bt@w_out + b_out
// ---- intermediates (ws scratch past the table) ----
constexpr int XG   = 3072;  // 608  G[k*32+e]
constexpr int XA2  = 3680;  // 608  A2[d*19+j]
constexpr int XMK  = 4288;  // 96   Mk[m*32+c]
constexpr int XMV  = 4384;  // 96   Mv[m*32+c]
constexpr int XGK  = 4480;  // 608  Gk[k*32+c]
constexpr int XGV  = 5088;  // 608  Gv[k*32+c]
constexpr int XB   = 5696;  // 608  B[c*19+j]

// Constant-address-space cast: lane-uniform loads through this pointer
// compile to s_load -> SGPR operands for the FMAs.
#define CONST_AS __attribute__((address_space(4)))
__device__ __forceinline__ const CONST_AS float* to_const(const float* p) {
    return (const CONST_AS float*)p;
}

// =====================================================================
// Precompute stage A: everything independent (wide, one elem per thread)
// =====================================================================
__global__ __launch_bounds__(256) void pre_a(
    const float* __restrict__ z,
    const float* __restrict__ sw1,
    const float* __restrict__ bn_gamma, const float* __restrict__ bn_beta,
    const float* __restrict__ bn_mean,  const float* __restrict__ bn_var,
    const float* __restrict__ sw2,      const float* __restrict__ sb2,
    const float* __restrict__ wq, const float* __restrict__ bq,
    const float* __restrict__ wk, const float* __restrict__ bk,
    const float* __restrict__ wv,
    const float* __restrict__ wt, const float* __restrict__ bt,
    const float* __restrict__ wout, const float* __restrict__ bout,
    const float* __restrict__ wgen, const float* __restrict__ bgen,
    float* __restrict__ W)
{
    int i = blockIdx.x * 256 + threadIdx.x;
    if (i < 1024) {                       // SW1T[c*32+e] = sw1[e*32+c]
        W[OFF_SW1 + i] = sw1[(i & 31) * 32 + (i >> 5)];
    } else if (i < 1632) {                // A1, A2
        int t = i - 1024, e = t / 19, j = t % 19;
        float a1 = 0.f, a2 = 0.f;
        for (int d = 0; d < 32; ++d) {
            float w_ = wout[d*19 + j];
            a1 += wt[e*32 + d] * w_;
            a2 += wt[(32 + e)*32 + d] * w_;
        }
        W[OFF_A1 + t] = a1; W[XA2 + t] = a2;
    } else if (i < 2240) {                // G[k*32+e] = g0[e] + wc[k][e]
        int t = i - 1632, k = t >> 5, e = t & 31;
        float g = bgen[e];
        for (int d = 0; d < 16; ++d) g += z[d] * wgen[d*32 + e];
        W[XG + t] = g + wgen[(16 + k)*32 + e];
    } else if (i < 2336) {                // Mk, Mv
        int t = i - 2240, m = t >> 5, c = t & 31;
        float a = 0.f, b = 0.f;
        for (int e = 0; e < 32; ++e) {
            float wsr = wgen[(35 + m)*32 + e];
            a += wsr * wk[e*32 + c];
            b += wsr * wv[e*32 + c];
        }
        W[XMK + t] = a; W[XMV + t] = b;
    } else if (i < 2368) {                // BN fold + SW2
        int t = i - 2336;
        float scale = bn_gamma[t] / sqrtf(bn_var[t] + 1e-4f);
        W[OFF_BNS + t] = scale;
        W[OFF_BNH + t] = bn_beta[t] - bn_mean[t] * scale;
        W[OFF_SW2 + t] = sw2[t];
    } else if (i < 2387) {                // bb = bt@wout + bout
        int t = i - 2368;
        float a = bout[t];
        for (int d = 0; d < 32; ++d) a += bt[d] * wout[d*19 + t];
        W[OFF_BB + t] = a;
    } else if (i < 2419) {                // qbv = wq @ bk
        int t = i - 2387;
        float a = 0.f;
        for (int c = 0; c < 32; ++c) a += wq[t*32 + c] * bk[c];
        W[OFF_QBV + t] = a;
    } else if (i == 2419) {               // b2
        W[OFF_B2] = sb2[0];
    } else if (i == 2420) {               // qbb = bq . bk
        float a = 0.f;
        for (int c = 0; c < 32; ++c) a += bq[c] * bk[c];
        W[OFF_QBB] = a;
    }
}

// =====================================================================
// Precompute stage B: Gk, Gv, B, QM, QMB (reads A's intermediates)
// =====================================================================
__global__ __launch_bounds__(256) void pre_b(
    const float* __restrict__ wq, const float* __restrict__ bq,
    const float* __restrict__ wk, const float* __restrict__ wv,
    const float* __restrict__ wo,
    float* __restrict__ W)
{
    int i = blockIdx.x * 256 + threadIdx.x;
    if (i < 608) {                        // Gk, Gv  [k*32+c]
        int k = i >> 5, c = i & 31;
        float a = 0.f, b = 0.f;
        for (int e = 0; e < 32; ++e) {
            float g = W[XG + k*32 + e];
            a += g * wk[e*32 + c];
            b += g * wv[e*32 + c];
        }
        W[XGK + i] = a; W[XGV + i] = b;
    } else if (i < 1216) {                // B[c*19+j] = wo @ A2
        int t = i - 608, c = t / 19, j = t % 19;
        float a = 0.f;
        for (int d = 0; d < 32; ++d) a += wo[c*32 + d] * W[XA2 + d*19 + j];
        W[XB + t] = a;
    } else if (i < 1312) {                // QM[e*3+m] = wq @ Mk^T
        int t = i - 1216, e = t / 3, m = t % 3;
        float a = 0.f;
        for (int c = 0; c < 32; ++c) a += wq[e*32 + c] * W[XMK + m*32 + c];
        W[OFF_QM + t] = a;
    } else if (i < 1315) {                // QMB[m] = bq @ Mk^T
        int m = i - 1312;
        float a = 0.f;
        for (int c = 0; c < 32; ++c) a += bq[c] * W[XMK + m*32 + c];
        W[OFF_QMB + m] = a;
    }
}

// =====================================================================
// Precompute stage C: QG, QGB, GVB, MVB, CV (reads B's intermediates)
// =====================================================================
__global__ __launch_bounds__(256) void pre_c(
    const float* __restrict__ wq, const float* __restrict__ bq,
    const float* __restrict__ bv, const float* __restrict__ bo,
    float* __restrict__ W)
{
    int i = blockIdx.x * 256 + threadIdx.x;
    if (i < 608) {                        // QG[e*19+k] = wq @ Gk^T
        int e = i / 19, k = i % 19;
        float a = 0.f;
        for (int c = 0; c < 32; ++c) a += wq[e*32 + c] * W[XGK + k*32 + c];
        W[OFF_QG + i] = a;
    } else if (i < 627) {                 // QGB[k] = bq @ Gk^T
        int k = i - 608;
        float a = 0.f;
        for (int c = 0; c < 32; ++c) a += bq[c] * W[XGK + k*32 + c];
        W[OFF_QGB + k] = a;
    } else if (i < 988) {                 // GVB[k*19+j] = Gv @ B
        int t = i - 627, k = t / 19, j = t % 19;
        float a = 0.f;
        for (int c = 0; c < 32; ++c) a += W[XGV + k*32 + c] * W[XB + c*19 + j];
        W[OFF_GVB + t] = a;
    } else if (i < 1045) {                // MVB[m*19+j] = Mv @ B
        int t = i - 988, m = t / 19, j = t % 19;
        float a = 0.f;
        for (int c = 0; c < 32; ++c) a += W[XMV + m*32 + c] * W[XB + c*19 + j];
        W[OFF_MVB + t] = a;
    } else if (i < 1064) {                // CV[j] = bv@B + bo@A2
        int j = i - 1045;
        float a = 0.f;
        for (int c = 0; c < 32; ++c) a += bv[c] * W[XB + c*19 + j];
        for (int d = 0; d < 32; ++d) a += bo[d] * W[XA2 + d*19 + j];
        W[OFF_CV + j] = a;
    }
}

// =====================================================================
// Kernel 2: one point per thread; weights via constant addrspace (s_load)
// (unchanged from round 4 — control for attribution)
// =====================================================================
__global__ __launch_bounds__(256, 1) void main_k(
    const float* __restrict__ feat,
    const float* __restrict__ sflow,
    const float* __restrict__ cpred,
    const float* __restrict__ Wg,
    float* __restrict__ out)
{
    const CONST_AS float* W = to_const(Wg);
    const int n = blockIdx.x * 256 + threadIdx.x;

    // ---- load feat row (32 f32, 128B aligned) ----
    float f[32];
    const float4* fp = (const float4*)(feat + (long)n * 32);
#pragma unroll
    for (int g = 0; g < 8; ++g) {
        float4 v = fp[g];
        f[g*4+0] = v.x; f[g*4+1] = v.y; f[g*4+2] = v.z; f[g*4+3] = v.w;
    }

    // ---- scene_flow + temp mask ----
    float s0 = sflow[(long)n*3 + 0];
    float s1 = sflow[(long)n*3 + 1];
    float s2 = sflow[(long)n*3 + 2];
    bool tmask = (s0 != 0.f) | (s1 != 0.f) | (s2 != 0.f);

    // ---- softmax(coarse_pred) ----
    float cp[19];
#pragma unroll
    for (int k = 0; k < 19; ++k) cp[k] = cpred[(long)n*19 + k];
    float m1 = cp[0];
#pragma unroll
    for (int k = 1; k < 19; ++k) m1 = fmaxf(m1, cp[k]);
    float sum1 = 0.f;
#pragma unroll
    for (int k = 0; k < 19; ++k) { cp[k] = __expf(cp[k] - m1); sum1 += cp[k]; }
    float r1 = 1.f / sum1;
#pragma unroll
    for (int k = 0; k < 19; ++k) cp[k] *= r1;

    // ---- selection score: SW1T row-contiguous per c ----
    float sacc = W[OFF_B2];
#pragma unroll
    for (int c = 0; c < 32; ++c) {
        float a = 0.f;
#pragma unroll
        for (int e = 0; e < 32; ++e) a = fmaf(f[e], W[OFF_SW1 + c*32 + e], a);
        float h = fmaf(a, W[OFF_BNS + c], W[OFF_BNH + c]);
        h = fmaxf(h, 0.f);
        sacc = fmaf(h, W[OFF_SW2 + c], sacc);
    }
    // sigmoid(s) < 0.8  <=>  s < ln(4)
    bool valid = tmask && (sacc < 1.3862943611198906f);

    // ---- attention logits via folded weights ----
    float qg[19];
#pragma unroll
    for (int k = 0; k < 19; ++k) qg[k] = W[OFF_QGB + k];
    float qm0 = W[OFF_QMB + 0], qm1 = W[OFF_QMB + 1], qm2 = W[OFF_QMB + 2];
    float qb = W[OFF_QBB];
#pragma unroll
    for (int e = 0; e < 32; ++e) {
        float fe = f[e];
#pragma unroll
        for (int k = 0; k < 19; ++k) qg[k] = fmaf(fe, W[OFF_QG + e*19 + k], qg[k]);
        qm0 = fmaf(fe, W[OFF_QM + e*3 + 0], qm0);
        qm1 = fmaf(fe, W[OFF_QM + e*3 + 1], qm1);
        qm2 = fmaf(fe, W[OFF_QM + e*3 + 2], qm2);
        qb  = fmaf(fe, W[OFF_QBV + e], qb);
    }
    float qs = s0*qm0 + s1*qm1 + s2*qm2;

    const float RS = 0.17677669529663687f;  // 1/sqrt(32)
    float l[19];
#pragma unroll
    for (int k = 0; k < 19; ++k) l[k] = fmaf(cp[k], qg[k] + qs, qb) * RS;

    // ---- softmax(l) → attn;  w[k] = attn[k]*cp[k];  Sw = sum w ----
    float m2 = l[0];
#pragma unroll
    for (int k = 1; k < 19; ++k) m2 = fmaxf(m2, l[k]);
    float sum2 = 0.f;
#pragma unroll
    for (int k = 0; k < 19; ++k) { l[k] = __expf(l[k] - m2); sum2 += l[k]; }
    float r2 = 1.f / sum2;
    float Sw = 0.f;
#pragma unroll
    for (int k = 0; k < 19; ++k) { l[k] = l[k] * r2 * cp[k]; Sw += l[k]; }

    // ---- o = bb + f@A1 ----
    float o[19];
#pragma unroll
    for (int j = 0; j < 19; ++j) o[j] = W[OFF_BB + j];
#pragma unroll
    for (int e = 0; e < 32; ++e) {
        float fe = f[e];
#pragma unroll
        for (int j = 0; j < 19; ++j) o[j] = fmaf(fe, W[OFF_A1 + e*19 + j], o[j]);
    }

    // ---- gated part: a2 = cv + Sw*(sf@MVB) + w@GVB ----
    float a2[19];
#pragma unroll
    for (int j = 0; j < 19; ++j) a2[j] = W[OFF_CV + j];
    float c0 = Sw * s0, c1 = Sw * s1, c2 = Sw * s2;
#pragma unroll
    for (int j = 0; j < 19; ++j) a2[j] = fmaf(c0, W[OFF_MVB + j], a2[j]);
#pragma unroll
    for (int j = 0; j < 19; ++j) a2[j] = fmaf(c1, W[OFF_MVB + 19 + j], a2[j]);
#pragma unroll
    for (int j = 0; j < 19; ++j) a2[j] = fmaf(c2, W[OFF_MVB + 38 + j], a2[j]);
#pragma unroll
    for (int k = 0; k < 19; ++k) {
        float lk = l[k];
#pragma unroll
        for (int j = 0; j < 19; ++j) a2[j] = fmaf(lk, W[OFF_GVB + k*19 + j], a2[j]);
    }

    float vg = valid ? 1.f : 0.f;
    // ---- store 19 f32 ----
    float* op = out + (long)n * 19;
#pragma unroll
    for (int j = 0; j < 19; ++j) op[j] = fmaf(vg, a2[j], o[j]);
}

// =====================================================================
extern "C" void kernel_launch(void* const* d_in, const int* in_sizes, int n_in,
                              void* d_out, int out_size, void* d_ws, size_t ws_size,
                              hipStream_t stream) {
    const float* feat  = (const float*)d_in[0];
    const float* sflow = (const float*)d_in[1];
    const float* cpred = (const float*)d_in[2];
    const float* z     = (const float*)d_in[3];
    const float* sw1   = (const float*)d_in[4];
    const float* bn_g  = (const float*)d_in[5];
    const float* bn_b  = (const float*)d_in[6];
    const float* bn_m  = (const float*)d_in[7];
    const float* bn_v  = (const float*)d_in[8];
    const float* sw2   = (const float*)d_in[9];
    const float* sb2   = (const float*)d_in[10];
    const float* wq    = (const float*)d_in[11];
    const float* bq    = (const float*)d_in[12];
    const float* wk    = (const float*)d_in[13];
    const float* bk    = (const float*)d_in[14];
    const float* wv    = (const float*)d_in[15];
    const float* bv    = (const float*)d_in[16];
    const float* wo    = (const float*)d_in[17];
    const float* bo    = (const float*)d_in[18];
    const float* wt    = (const float*)d_in[19];
    const float* bt    = (const float*)d_in[20];
    const float* wout  = (const float*)d_in[21];
    const float* bout  = (const float*)d_in[22];
    const float* wgen  = (const float*)d_in[23];
    const float* bgen  = (const float*)d_in[24];

    float* W = (float*)d_ws;

    hipLaunchKernelGGL(pre_a, dim3(10), dim3(256), 0, stream,
                       z, sw1, bn_g, bn_b, bn_m, bn_v, sw2, sb2,
                       wq, bq, wk, bk, wv, wt, bt, wout, bout, wgen, bgen, W);
    hipLaunchKernelGGL(pre_b, dim3(6), dim3(256), 0, stream,
                       wq, bq, wk, wv, wo, W);
    hipLaunchKernelGGL(pre_c, dim3(5), dim3(256), 0, stream,
                       wq, bq, bv, bo, W);

    hipLaunchKernelGGL(main_k, dim3(NPTS / 256), dim3(256), 0, stream,
                       feat, sflow, cpred, W, (float*)d_out);
}